// Round 4
// baseline (199.686 us; speedup 1.0000x reference)
//
#include <hip/hip_runtime.h>
#include <hip/hip_bf16.h>
#include <float.h>

// MoE: n=4096 tokens, D=O=512, E=8, top-2, 3-layer ReLU MLP per expert.
// out[n] = p[n,0]*MLP_{e0}(x[n]) + p[n,1]*MLP_{e1}(x[n])   (slot-indexed probs quirk)
//
// Round-4 structure: ONE fused kernel runs all 3 layers per 64-row expert tile.
//  - h resides in LDS (64 KB, XOR-swizzled cols) across layers; never touches global.
//  - W streams global->VGPR with plain vector loads (no global_load_lds, no per-iter
//    barriers) so the compiler software-pipelines loads across MFMAs (vmcnt != 0).
//  - Waves split the 512 output columns (disjoint W traffic).
//  - Layer 3 scatters entry_w * relu(y) into out via f32 atomics (no combine pass).

#define NTOK   4096
#define DIM    512
#define NEXP   8
#define NENT   (NTOK * 2)
#define CAP    8704
#define MAXT   136

typedef _Float16 half8 __attribute__((ext_vector_type(8)));
typedef float    f32x4 __attribute__((ext_vector_type(4)));

// ---- workspace layout (bytes) ----
#define META_OFF   0u          // int[64]: [0..7] counts, [8..15] cursors, [16] ntiles, [24..31] padded offs
#define TILE_E_OFF 1024u       // int[160]
#define TILE_R_OFF 2048u       // int[160]
#define TOPE_OFF   4096u       // int[8192]
#define TOPW_OFF   36864u      // float[8192]
#define ETOK_OFF   69632u      // int[CAP]
#define EW_OFF     104448u     // float[CAP]
#define XH_OFF     139264u     // f16[4096*512] = 4 MB
#define WT_OFF     4333568u    // f16[24*512*512] = 12.6 MB ([l][e][n][k])
// total ~16.9 MB

// col swizzle: element (row, col) stored at col ^ swz(row); keeps 8-elem runs
// contiguous (swz is a multiple of 8) and spreads the 4 row-quads of a C/D
// write ({r, r+4, r+8, r+12}) across disjoint bank quartets.
__device__ __forceinline__ int swz(int row) {
    return ((row & 7) << 3) ^ ((row & 8) << 1);
}

// ---------------- gate + convert_x + count, fused ----------------
__global__ __launch_bounds__(256)
void gate_kernel(const float* __restrict__ x, const float* __restrict__ gw,
                 const float* __restrict__ gb,
                 int* __restrict__ top_e, float* __restrict__ top_w,
                 _Float16* __restrict__ xh, int* __restrict__ meta)
{
    __shared__ int scnt[NEXP];
    int tid = threadIdx.x;
    if (tid < NEXP) scnt[tid] = 0;
    __syncthreads();

    int n = blockIdx.x * 4 + (tid >> 6);
    int lane = tid & 63;
    const float* xr = x + (size_t)n * DIM + lane * 8;
    float4 v0 = *(const float4*)xr;
    float4 v1 = *(const float4*)(xr + 4);
    float xv[8] = {v0.x, v0.y, v0.z, v0.w, v1.x, v1.y, v1.z, v1.w};

    half8 h = { (_Float16)xv[0], (_Float16)xv[1], (_Float16)xv[2], (_Float16)xv[3],
                (_Float16)xv[4], (_Float16)xv[5], (_Float16)xv[6], (_Float16)xv[7] };
    *(half8*)(xh + (size_t)n * DIM + lane * 8) = h;

    float p[NEXP];
#pragma unroll
    for (int e = 0; e < NEXP; e++) p[e] = 0.f;
    const float* g = gw + (size_t)lane * 64;
#pragma unroll
    for (int j = 0; j < 8; j++)
#pragma unroll
        for (int e = 0; e < NEXP; e++) p[e] += xv[j] * g[j * 8 + e];
#pragma unroll
    for (int e = 0; e < NEXP; e++) {
        float v = p[e];
        for (int off = 32; off; off >>= 1) v += __shfl_xor(v, off, 64);
        p[e] = v;
    }
    if (lane == 0) {
        float l[NEXP];
#pragma unroll
        for (int e = 0; e < NEXP; e++) l[e] = p[e] + gb[e];
        float m = l[0];
#pragma unroll
        for (int e = 1; e < NEXP; e++) m = fmaxf(m, l[e]);
        float ex[NEXP], s = 0.f;
#pragma unroll
        for (int e = 0; e < NEXP; e++) { ex[e] = expf(l[e] - m); s += ex[e]; }
        int e0 = 0; float m0 = l[0];
#pragma unroll
        for (int e = 1; e < NEXP; e++) if (l[e] > m0) { m0 = l[e]; e0 = e; }
        int e1 = -1; float m1 = -FLT_MAX;
#pragma unroll
        for (int e = 0; e < NEXP; e++) if (e != e0 && l[e] > m1) { m1 = l[e]; e1 = e; }
        float inv = 1.f / s;
        top_e[2 * n + 0] = e0;
        top_e[2 * n + 1] = e1;
        top_w[2 * n + 0] = ex[0] * inv;   // slot-indexed probs (reference quirk)
        top_w[2 * n + 1] = ex[1] * inv;
        atomicAdd(&scnt[e0], 1);
        atomicAdd(&scnt[e1], 1);
    }
    __syncthreads();
    if (tid < NEXP) atomicAdd(&meta[tid], scnt[tid]);
}

// ---------------- scan + tile map (64-row tiles) ----------------
__global__ __launch_bounds__(64)
void scan_kernel(int* __restrict__ meta, int* __restrict__ tile_e, int* __restrict__ tile_r)
{
    if (threadIdx.x == 0 && blockIdx.x == 0) {
        int off = 0, nt = 0;
        for (int e = 0; e < NEXP; e++) {
            int c = meta[e];
            meta[24 + e] = off;
            int tiles = (c + 63) >> 6;
            for (int t = 0; t < tiles; t++) { tile_e[nt] = e; tile_r[nt] = off + (t << 6); nt++; }
            off += tiles << 6;
        }
        meta[16] = nt;
        meta[17] = off;
    }
}

// ---------------- scatter tokens into per-expert gathered lists ----------------
__global__ __launch_bounds__(256)
void scatter_kernel(const int* __restrict__ top_e, const float* __restrict__ top_w,
                    int* __restrict__ meta, int* __restrict__ entry_tok,
                    float* __restrict__ entry_w)
{
    int n = blockIdx.x * 256 + threadIdx.x;
    int lane = threadIdx.x & 63;
#pragma unroll
    for (int j = 0; j < 2; j++) {
        int e = top_e[2 * n + j];
        float ww = top_w[2 * n + j];
        int pos = 0;
        for (int ex = 0; ex < NEXP; ex++) {
            unsigned long long m = __ballot(e == ex);
            if (e == ex) {
                int leader = __ffsll(m) - 1;
                int base = 0;
                if (lane == leader) base = atomicAdd(&meta[8 + ex], __popcll(m));
                base = __shfl(base, leader, 64);
                pos = meta[24 + ex] + base + __popcll(m & ((1ull << lane) - 1ull));
            }
        }
        entry_tok[pos] = n;
        entry_w[pos] = ww;
    }
}

// ---------------- transpose+convert weights: [l][e][k][n] -> [l][e][n][k] fp16 ----------------
__global__ __launch_bounds__(256)
void transpose_w(const float* __restrict__ W1, const float* __restrict__ W2,
                 const float* __restrict__ W3, _Float16* __restrict__ Wt)
{
    __shared__ float t[32][33];
    int mat = blockIdx.z;
    const float* src = (mat < 8) ? W1 + (size_t)mat * DIM * DIM
                     : (mat < 16) ? W2 + (size_t)(mat - 8) * DIM * DIM
                                  : W3 + (size_t)(mat - 16) * DIM * DIM;
    _Float16* dst = Wt + (size_t)mat * DIM * DIM;
    int tx = threadIdx.x & 31, ty = threadIdx.x >> 5;
    int x0 = blockIdx.x * 32, y0 = blockIdx.y * 32;
#pragma unroll
    for (int j = 0; j < 4; j++)
        t[ty + 8 * j][tx] = src[(size_t)(y0 + ty + 8 * j) * DIM + x0 + tx];
    __syncthreads();
#pragma unroll
    for (int j = 0; j < 4; j++)
        dst[(size_t)(x0 + ty + 8 * j) * DIM + y0 + tx] = (_Float16)t[tx][ty + 8 * j];
}

// ---------------- fused 3-layer expert MLP: one block per 64-row tile ----------------
__global__ __launch_bounds__(256, 1)
void fused_mlp(const _Float16* __restrict__ xh, const _Float16* __restrict__ wt,
               const float* __restrict__ b1, const float* __restrict__ b2,
               const float* __restrict__ b3, float* __restrict__ out,
               const int* __restrict__ meta, const int* __restrict__ tile_e,
               const int* __restrict__ tile_r, const int* __restrict__ entry_tok,
               const float* __restrict__ entry_w)
{
    __shared__ _Float16 hbuf[64 * DIM];   // 65536 B exactly; swizzled cols

    int tile = blockIdx.x;
    if (tile >= meta[16]) return;
    int e = tile_e[tile];
    int row0 = tile_r[tile];

    int tid = threadIdx.x;
    int w = tid >> 6, l = tid & 63;
    int l15 = l & 15, l4 = l >> 4;

    // ---- fill hbuf with gathered x rows (4 threads per row) ----
    {
        int row = tid >> 2;
        int c0 = (tid & 3) * 128;
        int tk = entry_tok[row0 + row];
        if (tk < 0) tk = 0;                        // pad rows: garbage ok, dropped at scatter
        const _Float16* src = xh + (size_t)tk * DIM + c0;
        int f = swz(row);
        _Float16* dst = hbuf + row * DIM;
#pragma unroll
        for (int j = 0; j < 16; j++) {
            half8 v = *(const half8*)(src + j * 8);
            *(half8*)(dst + ((c0 + j * 8) ^ f)) = v;
        }
    }
    __syncthreads();

    f32x4 acc[4][8];
    int colb = w * 128 + l15;                     // this lane's column base (per cg: +16*cg)

    // one layer of MFMA: A from hbuf (all 64 rows), B streamed from global (wave's 128 cols)
    auto run_layer = [&](const _Float16* __restrict__ W) {
#pragma unroll
        for (int rg = 0; rg < 4; rg++)
#pragma unroll
            for (int cg = 0; cg < 8; cg++) acc[rg][cg] = (f32x4){0.f, 0.f, 0.f, 0.f};
        for (int kc = 0; kc < 16; kc++) {
            int koff = kc * 32 + l4 * 8;
            half8 af[4];
#pragma unroll
            for (int rg = 0; rg < 4; rg++) {
                int row = rg * 16 + l15;
                af[rg] = *(const half8*)(hbuf + row * DIM + (koff ^ swz(row)));
            }
            half8 bf[8];
#pragma unroll
            for (int cg = 0; cg < 8; cg++)
                bf[cg] = *(const half8*)(W + (size_t)(colb + cg * 16) * DIM + koff);
#pragma unroll
            for (int rg = 0; rg < 4; rg++)
#pragma unroll
                for (int cg = 0; cg < 8; cg++)
                    acc[rg][cg] = __builtin_amdgcn_mfma_f32_16x16x32_f16(af[rg], bf[cg], acc[rg][cg], 0, 0, 0);
        }
    };

    // relu(acc + bias) -> hbuf (becomes next layer's A), C/D layout: col=l&15(+16cg), row=l4*4+r(+16rg)
    auto writeback = [&](const float* __restrict__ Bias) {
        float bs[8];
#pragma unroll
        for (int cg = 0; cg < 8; cg++) bs[cg] = Bias[e * DIM + colb + cg * 16];
        __syncthreads();                          // all hbuf reads of this layer done
#pragma unroll
        for (int rg = 0; rg < 4; rg++)
#pragma unroll
            for (int r = 0; r < 4; r++) {
                int row = rg * 16 + l4 * 4 + r;
                int f = swz(row);
                _Float16* dst = hbuf + row * DIM;
#pragma unroll
                for (int cg = 0; cg < 8; cg++) {
                    int col = colb + cg * 16;
                    dst[col ^ f] = (_Float16)fmaxf(acc[rg][cg][r] + bs[cg], 0.f);
                }
            }
        __syncthreads();                          // next layer may read
    };

    const size_t MSZ = (size_t)DIM * DIM;
    run_layer(wt + ((size_t)e) * MSZ);            writeback(b1);
    run_layer(wt + ((size_t)(8 + e)) * MSZ);      writeback(b2);
    run_layer(wt + ((size_t)(16 + e)) * MSZ);

    // ---- layer-3 epilogue: out[tok] += entry_w * relu(acc + b3), f32 atomics ----
    float bs[8];
#pragma unroll
    for (int cg = 0; cg < 8; cg++) bs[cg] = b3[e * DIM + colb + cg * 16];
#pragma unroll
    for (int rg = 0; rg < 4; rg++)
#pragma unroll
        for (int r = 0; r < 4; r++) {
            int row = rg * 16 + l4 * 4 + r;
            int gidx = row0 + row;
            int tok = entry_tok[gidx];
            if (tok >= 0) {
                float ww = entry_w[gidx];
                float* op = out + (size_t)tok * DIM + colb;
#pragma unroll
                for (int cg = 0; cg < 8; cg++) {
                    float v = fmaxf(acc[rg][cg][r] + bs[cg], 0.f);
                    atomicAdd(op + cg * 16, ww * v);
                }
            }
        }
}

extern "C" void kernel_launch(void* const* d_in, const int* in_sizes, int n_in,
                              void* d_out, int out_size, void* d_ws, size_t ws_size,
                              hipStream_t stream)
{
    const float* x      = (const float*)d_in[0];
    const float* gate_w = (const float*)d_in[1];
    const float* gate_b = (const float*)d_in[2];
    const float* w1     = (const float*)d_in[3];
    const float* b1     = (const float*)d_in[4];
    const float* w2     = (const float*)d_in[5];
    const float* b2     = (const float*)d_in[6];
    const float* w3     = (const float*)d_in[7];
    const float* b3     = (const float*)d_in[8];
    float* out = (float*)d_out;

    char* ws = (char*)d_ws;
    int*      meta      = (int*)(ws + META_OFF);
    int*      tile_e    = (int*)(ws + TILE_E_OFF);
    int*      tile_r    = (int*)(ws + TILE_R_OFF);
    int*      top_e     = (int*)(ws + TOPE_OFF);
    float*    top_w     = (float*)(ws + TOPW_OFF);
    int*      entry_tok = (int*)(ws + ETOK_OFF);
    float*    entry_w   = (float*)(ws + EW_OFF);
    _Float16* xh        = (_Float16*)(ws + XH_OFF);
    _Float16* wt        = (_Float16*)(ws + WT_OFF);

    hipMemsetAsync(meta, 0, 256, stream);
    hipMemsetAsync(out, 0, (size_t)out_size * sizeof(float), stream);

    gate_kernel<<<NTOK / 4, 256, 0, stream>>>(x, gate_w, gate_b, top_e, top_w, xh, meta);
    scan_kernel<<<1, 64, 0, stream>>>(meta, tile_e, tile_r);
    scatter_kernel<<<NTOK / 256, 256, 0, stream>>>(top_e, top_w, meta, entry_tok, entry_w);
    transpose_w<<<dim3(16, 16, 24), 256, 0, stream>>>(w1, w2, w3, wt);

    fused_mlp<<<MAXT, 256, 0, stream>>>(xh, wt, b1, b2, b3, out,
                                        meta, tile_e, tile_r, entry_tok, entry_w);
}

// Round 5
// 191.747 us; speedup vs baseline: 1.0414x; 1.0414x over previous
//
#include <hip/hip_runtime.h>
#include <hip/hip_bf16.h>
#include <float.h>

// MoE: n=4096 tokens, D=O=512, E=8, top-2, 3-layer ReLU MLP per expert.
// out[n] = p[n,0]*MLP_{e0}(x[n]) + p[n,1]*MLP_{e1}(x[n])   (slot-indexed probs quirk)
//
// Round-5: fused 3-layer kernel, one block per 64-row expert tile.
//  - 512 threads (8 waves, 2/SIMD) so load stalls of one wave hide under the
//    other's MFMAs; W streams global->VGPR with a register double-buffer
//    (kc+1 loads in flight during kc's MFMAs -> vmcnt(N) pipelining).
//  - Expert->XCD affinity: grid b in [0,1024), e = b&7, tile j = b>>3.
//    Round-robin block->XCD dispatch puts all blocks of expert e on XCD e;
//    its full 1.5 MB weight set fits that XCD's 4 MB L2 (pure perf heuristic).
//  - h lives in 64 KB XOR-swizzled LDS across layers; layer-3 scatters
//    entry_w * relu(y) into out via f32 atomics.

#define NTOK   4096
#define DIM    512
#define NEXP   8
#define NENT   (NTOK * 2)
#define CAP    8704
#define MAXTE  128                 // worst-case 64-row tiles per expert

typedef _Float16 half8 __attribute__((ext_vector_type(8)));
typedef float    f32x4 __attribute__((ext_vector_type(4)));

// ---- workspace layout (bytes) ----
#define META_OFF   0u          // int[64]: [0..7] counts, [8..15] cursors, [24..31] padded offs
#define TOPE_OFF   4096u       // int[8192]
#define TOPW_OFF   36864u      // float[8192]
#define ETOK_OFF   69632u      // int[CAP]
#define EW_OFF     104448u     // float[CAP]
#define XH_OFF     139264u     // f16[4096*512] = 4 MB
#define WT_OFF     4333568u    // f16[24*512*512] = 12.6 MB ([l][e][n][k])

// col swizzle: element (row, col) stored at col ^ swz(row); multiples of 8 keep
// half8 runs contiguous; spreads the C/D row-quads {r,r+4,r+8,r+12} across
// disjoint bank quartets.
__device__ __forceinline__ int swz(int row) {
    return ((row & 7) << 3) ^ ((row & 8) << 1);
}

// ---------------- gate + convert_x + count, fused ----------------
__global__ __launch_bounds__(256)
void gate_kernel(const float* __restrict__ x, const float* __restrict__ gw,
                 const float* __restrict__ gb,
                 int* __restrict__ top_e, float* __restrict__ top_w,
                 _Float16* __restrict__ xh, int* __restrict__ meta)
{
    __shared__ int scnt[NEXP];
    int tid = threadIdx.x;
    if (tid < NEXP) scnt[tid] = 0;
    __syncthreads();

    int n = blockIdx.x * 4 + (tid >> 6);
    int lane = tid & 63;
    const float* xr = x + (size_t)n * DIM + lane * 8;
    float4 v0 = *(const float4*)xr;
    float4 v1 = *(const float4*)(xr + 4);
    float xv[8] = {v0.x, v0.y, v0.z, v0.w, v1.x, v1.y, v1.z, v1.w};

    half8 h = { (_Float16)xv[0], (_Float16)xv[1], (_Float16)xv[2], (_Float16)xv[3],
                (_Float16)xv[4], (_Float16)xv[5], (_Float16)xv[6], (_Float16)xv[7] };
    *(half8*)(xh + (size_t)n * DIM + lane * 8) = h;

    float p[NEXP];
#pragma unroll
    for (int e = 0; e < NEXP; e++) p[e] = 0.f;
    const float* g = gw + (size_t)lane * 64;
#pragma unroll
    for (int j = 0; j < 8; j++)
#pragma unroll
        for (int e = 0; e < NEXP; e++) p[e] += xv[j] * g[j * 8 + e];
#pragma unroll
    for (int e = 0; e < NEXP; e++) {
        float v = p[e];
        for (int off = 32; off; off >>= 1) v += __shfl_xor(v, off, 64);
        p[e] = v;
    }
    if (lane == 0) {
        float l[NEXP];
#pragma unroll
        for (int e = 0; e < NEXP; e++) l[e] = p[e] + gb[e];
        float m = l[0];
#pragma unroll
        for (int e = 1; e < NEXP; e++) m = fmaxf(m, l[e]);
        float ex[NEXP], s = 0.f;
#pragma unroll
        for (int e = 0; e < NEXP; e++) { ex[e] = expf(l[e] - m); s += ex[e]; }
        int e0 = 0; float m0 = l[0];
#pragma unroll
        for (int e = 1; e < NEXP; e++) if (l[e] > m0) { m0 = l[e]; e0 = e; }
        int e1 = -1; float m1 = -FLT_MAX;
#pragma unroll
        for (int e = 0; e < NEXP; e++) if (e != e0 && l[e] > m1) { m1 = l[e]; e1 = e; }
        float inv = 1.f / s;
        top_e[2 * n + 0] = e0;
        top_e[2 * n + 1] = e1;
        top_w[2 * n + 0] = ex[0] * inv;   // slot-indexed probs (reference quirk)
        top_w[2 * n + 1] = ex[1] * inv;
        atomicAdd(&scnt[e0], 1);
        atomicAdd(&scnt[e1], 1);
    }
    __syncthreads();
    if (tid < NEXP) atomicAdd(&meta[tid], scnt[tid]);
}

// ---------------- scan: per-expert padded base offsets ----------------
__global__ __launch_bounds__(64)
void scan_kernel(int* __restrict__ meta)
{
    if (threadIdx.x == 0 && blockIdx.x == 0) {
        int off = 0;
        for (int e = 0; e < NEXP; e++) {
            meta[24 + e] = off;
            off += ((meta[e] + 63) >> 6) << 6;
        }
    }
}

// ---------------- scatter tokens into per-expert gathered lists ----------------
__global__ __launch_bounds__(256)
void scatter_kernel(const int* __restrict__ top_e, const float* __restrict__ top_w,
                    int* __restrict__ meta, int* __restrict__ entry_tok,
                    float* __restrict__ entry_w)
{
    int n = blockIdx.x * 256 + threadIdx.x;
    int lane = threadIdx.x & 63;
#pragma unroll
    for (int j = 0; j < 2; j++) {
        int e = top_e[2 * n + j];
        float ww = top_w[2 * n + j];
        int pos = 0;
        for (int ex = 0; ex < NEXP; ex++) {
            unsigned long long m = __ballot(e == ex);
            if (e == ex) {
                int leader = __ffsll(m) - 1;
                int base = 0;
                if (lane == leader) base = atomicAdd(&meta[8 + ex], __popcll(m));
                base = __shfl(base, leader, 64);
                pos = meta[24 + ex] + base + __popcll(m & ((1ull << lane) - 1ull));
            }
        }
        entry_tok[pos] = n;
        entry_w[pos] = ww;
    }
}

// ---------------- transpose+convert weights: [l][e][k][n] -> [l][e][n][k] fp16 ----------------
__global__ __launch_bounds__(256)
void transpose_w(const float* __restrict__ W1, const float* __restrict__ W2,
                 const float* __restrict__ W3, _Float16* __restrict__ Wt)
{
    __shared__ float t[32][33];
    int mat = blockIdx.z;
    const float* src = (mat < 8) ? W1 + (size_t)mat * DIM * DIM
                     : (mat < 16) ? W2 + (size_t)(mat - 8) * DIM * DIM
                                  : W3 + (size_t)(mat - 16) * DIM * DIM;
    _Float16* dst = Wt + (size_t)mat * DIM * DIM;
    int tx = threadIdx.x & 31, ty = threadIdx.x >> 5;
    int x0 = blockIdx.x * 32, y0 = blockIdx.y * 32;
#pragma unroll
    for (int j = 0; j < 4; j++)
        t[ty + 8 * j][tx] = src[(size_t)(y0 + ty + 8 * j) * DIM + x0 + tx];
    __syncthreads();
#pragma unroll
    for (int j = 0; j < 4; j++)
        dst[(size_t)(x0 + ty + 8 * j) * DIM + y0 + tx] = (_Float16)t[tx][ty + 8 * j];
}

// ---------------- fused 3-layer expert MLP ----------------
__global__ __launch_bounds__(512, 1)
void fused_mlp(const _Float16* __restrict__ xh, const _Float16* __restrict__ wt,
               const float* __restrict__ b1, const float* __restrict__ b2,
               const float* __restrict__ b3, float* __restrict__ out,
               const int* __restrict__ meta, const int* __restrict__ entry_tok,
               const float* __restrict__ entry_w)
{
    __shared__ _Float16 hbuf[64 * DIM];   // 64 KB, swizzled cols
    __shared__ int   rtok[64];
    __shared__ float rw[64];

    int bid = blockIdx.x;
    int e = bid & 7;                       // XCD affinity: blockIdx % 8 -> XCD
    int j = bid >> 3;
    int cnt = meta[e];
    if (j >= ((cnt + 63) >> 6)) return;    // beyond this expert's tiles
    int row0 = meta[24 + e] + (j << 6);

    int tid = threadIdx.x;
    int w = tid >> 6, l = tid & 63;
    int l15 = l & 15, l4 = l >> 4;

    if (tid < 64) {
        rtok[tid] = entry_tok[row0 + tid]; // pad slots: poison (<0)
        rw[tid]   = entry_w[row0 + tid];
    }
    __syncthreads();

    // fill hbuf with gathered x rows: 8 threads/row, 64 cols each
    {
        int row = tid >> 3;
        int c0 = (tid & 7) * 64;
        int tk = rtok[row]; if (tk < 0) tk = 0;   // garbage ok, dropped at scatter
        const _Float16* src = xh + (size_t)tk * DIM + c0;
        int f = swz(row);
        _Float16* dst = hbuf + row * DIM;
#pragma unroll
        for (int q = 0; q < 8; q++) {
            half8 v = *(const half8*)(src + q * 8);
            *(half8*)(dst + ((c0 + q * 8) ^ f)) = v;
        }
    }
    __syncthreads();

    int colb = w * 64 + l15;               // wave w owns cols [w*64, w*64+64)
    f32x4 acc[4][4];

    // one layer: A from hbuf (64 rows), B register-dbuf streamed from global
    auto run_layer = [&](const _Float16* __restrict__ W) {
#pragma unroll
        for (int rg = 0; rg < 4; rg++)
#pragma unroll
            for (int cg = 0; cg < 4; cg++) acc[rg][cg] = (f32x4){0.f, 0.f, 0.f, 0.f};
        const _Float16* wp0 = W + (size_t)colb * DIM + l4 * 8;
        half8 bcur[4], bnxt[4];
#pragma unroll
        for (int cg = 0; cg < 4; cg++)
            bcur[cg] = *(const half8*)(wp0 + (size_t)(cg * 16) * DIM);
        for (int kc = 0; kc < 16; kc++) {
            if (kc < 15) {                 // next iter's B in flight during MFMAs
                const _Float16* wp = wp0 + (kc + 1) * 32;
#pragma unroll
                for (int cg = 0; cg < 4; cg++)
                    bnxt[cg] = *(const half8*)(wp + (size_t)(cg * 16) * DIM);
            }
            int koff = kc * 32 + l4 * 8;
            half8 af[4];
#pragma unroll
            for (int rg = 0; rg < 4; rg++) {
                int row = rg * 16 + l15;
                af[rg] = *(const half8*)(hbuf + row * DIM + (koff ^ swz(row)));
            }
#pragma unroll
            for (int rg = 0; rg < 4; rg++)
#pragma unroll
                for (int cg = 0; cg < 4; cg++)
                    acc[rg][cg] = __builtin_amdgcn_mfma_f32_16x16x32_f16(af[rg], bcur[cg], acc[rg][cg], 0, 0, 0);
#pragma unroll
            for (int cg = 0; cg < 4; cg++) bcur[cg] = bnxt[cg];
        }
    };

    // relu(acc + bias) -> hbuf; C/D layout: col=l&15(+16cg), row=l4*4+r(+16rg)
    auto writeback = [&](const float* __restrict__ Bias) {
        float bs[4];
#pragma unroll
        for (int cg = 0; cg < 4; cg++) bs[cg] = Bias[e * DIM + colb + cg * 16];
        __syncthreads();                   // all waves' hbuf reads done
#pragma unroll
        for (int rg = 0; rg < 4; rg++)
#pragma unroll
            for (int r = 0; r < 4; r++) {
                int row = rg * 16 + l4 * 4 + r;
                int f = swz(row);
                _Float16* dst = hbuf + row * DIM;
#pragma unroll
                for (int cg = 0; cg < 4; cg++)
                    dst[(colb + cg * 16) ^ f] = (_Float16)fmaxf(acc[rg][cg][r] + bs[cg], 0.f);
            }
        __syncthreads();
    };

    const size_t MSZ = (size_t)DIM * DIM;
    run_layer(wt + (size_t)e * MSZ);        writeback(b1);
    run_layer(wt + (size_t)(8 + e) * MSZ);  writeback(b2);
    run_layer(wt + (size_t)(16 + e) * MSZ);

    // layer-3 epilogue: out[tok] += entry_w * relu(acc + b3)
    float bs[4];
#pragma unroll
    for (int cg = 0; cg < 4; cg++) bs[cg] = b3[e * DIM + colb + cg * 16];
#pragma unroll
    for (int rg = 0; rg < 4; rg++)
#pragma unroll
        for (int r = 0; r < 4; r++) {
            int row = rg * 16 + l4 * 4 + r;
            int tok = rtok[row];
            if (tok >= 0) {
                float ww = rw[row];
                float* op = out + (size_t)tok * DIM + colb;
#pragma unroll
                for (int cg = 0; cg < 4; cg++) {
                    float v = fmaxf(acc[rg][cg][r] + bs[cg], 0.f);
                    atomicAdd(op + cg * 16, ww * v);
                }
            }
        }
}

extern "C" void kernel_launch(void* const* d_in, const int* in_sizes, int n_in,
                              void* d_out, int out_size, void* d_ws, size_t ws_size,
                              hipStream_t stream)
{
    const float* x      = (const float*)d_in[0];
    const float* gate_w = (const float*)d_in[1];
    const float* gate_b = (const float*)d_in[2];
    const float* w1     = (const float*)d_in[3];
    const float* b1     = (const float*)d_in[4];
    const float* w2     = (const float*)d_in[5];
    const float* b2     = (const float*)d_in[6];
    const float* w3     = (const float*)d_in[7];
    const float* b3     = (const float*)d_in[8];
    float* out = (float*)d_out;

    char* ws = (char*)d_ws;
    int*      meta      = (int*)(ws + META_OFF);
    int*      top_e     = (int*)(ws + TOPE_OFF);
    float*    top_w     = (float*)(ws + TOPW_OFF);
    int*      entry_tok = (int*)(ws + ETOK_OFF);
    float*    entry_w   = (float*)(ws + EW_OFF);
    _Float16* xh        = (_Float16*)(ws + XH_OFF);
    _Float16* wt        = (_Float16*)(ws + WT_OFF);

    hipMemsetAsync(meta, 0, 256, stream);
    hipMemsetAsync(out, 0, (size_t)out_size * sizeof(float), stream);

    gate_kernel<<<NTOK / 4, 256, 0, stream>>>(x, gate_w, gate_b, top_e, top_w, xh, meta);
    scan_kernel<<<1, 64, 0, stream>>>(meta);
    scatter_kernel<<<NTOK / 256, 256, 0, stream>>>(top_e, top_w, meta, entry_tok, entry_w);
    transpose_w<<<dim3(16, 16, 24), 256, 0, stream>>>(w1, w2, w3, wt);

    fused_mlp<<<NEXP * MAXTE, 512, 0, stream>>>(xh, wt, b1, b2, b3, out,
                                                meta, entry_tok, entry_w);
}

// Round 6
// 173.484 us; speedup vs baseline: 1.1510x; 1.1053x over previous
//
#include <hip/hip_runtime.h>
#include <hip/hip_bf16.h>
#include <float.h>

// MoE: n=4096 tokens, D=O=512, E=8, top-2, 3-layer ReLU MLP per expert.
// out[n] = p[n,0]*MLP_{e0}(x[n]) + p[n,1]*MLP_{e1}(x[n])   (slot-indexed probs quirk)
//
// Round-6: fused 3-layer kernel, one 256-thread block per 64-row expert tile.
//  - Wave tile = 64 rows x 128 cols: acc[4][8] (128 VGPRs), per kc-step
//    4 LDS reads + 8 global B loads feed 32 MFMAs (4x the MFMA/byte of r5).
//  - Zero B duplication across waves (disjoint 128-col strips).
//  - W pre-packed so each B fragment is ONE contiguous 1KB wave load.
//  - Register prefetch (depth 1) of next kc's B under current MFMAs.
//  - Expert->XCD affinity (e = bid&7) keeps each expert's 1.5MB in its L2.
//  - h stays in 64KB swizzled LDS; layer-3 scatters w*relu(y) via f32 atomics.

#define NTOK   4096
#define DIM    512
#define NEXP   8
#define CAP    8704
#define MAXTE  128
#define MATSZ  (DIM * DIM)         // f16 elems per matrix

typedef _Float16 half8 __attribute__((ext_vector_type(8)));
typedef float    f32x4 __attribute__((ext_vector_type(4)));

// ---- workspace layout (bytes) ----
#define META_OFF   0u          // int[64]: [0..7] counts, [8..15] cursors
#define TOPE_OFF   4096u       // int[8192]
#define TOPW_OFF   36864u      // float[8192]
#define ETOK_OFF   69632u      // int[CAP]
#define EW_OFF     104448u     // float[CAP]
#define XH_OFF     139264u     // f16[4096*512] = 4 MB
#define WT_OFF     4333568u    // f16[24*512*512] = 12.6 MB, packed (see pack_w)

// col swizzle: element (row,col) stored at col ^ swz(row); multiples of 8 keep
// half8 runs contiguous and spread C/D row-quads across bank groups.
__device__ __forceinline__ int swz(int row) {
    return ((row & 7) << 3) ^ ((row & 8) << 1);
}

// ---------------- gate + convert_x + count + zero-out, fused ----------------
__global__ __launch_bounds__(256)
void gate_kernel(const float* __restrict__ x, const float* __restrict__ gw,
                 const float* __restrict__ gb,
                 int* __restrict__ top_e, float* __restrict__ top_w,
                 _Float16* __restrict__ xh, int* __restrict__ meta,
                 float* __restrict__ out)
{
    __shared__ int scnt[NEXP];
    int tid = threadIdx.x;
    if (tid < NEXP) scnt[tid] = 0;
    __syncthreads();

    int n = blockIdx.x * 4 + (tid >> 6);
    int lane = tid & 63;

    // zero this token's out row (fused_mlp accumulates atomically later)
    float4 z = {0.f, 0.f, 0.f, 0.f};
    float* op = out + (size_t)n * DIM + lane * 8;
    *(float4*)op = z;
    *(float4*)(op + 4) = z;

    const float* xr = x + (size_t)n * DIM + lane * 8;
    float4 v0 = *(const float4*)xr;
    float4 v1 = *(const float4*)(xr + 4);
    float xv[8] = {v0.x, v0.y, v0.z, v0.w, v1.x, v1.y, v1.z, v1.w};

    half8 h = { (_Float16)xv[0], (_Float16)xv[1], (_Float16)xv[2], (_Float16)xv[3],
                (_Float16)xv[4], (_Float16)xv[5], (_Float16)xv[6], (_Float16)xv[7] };
    *(half8*)(xh + (size_t)n * DIM + lane * 8) = h;

    float p[NEXP];
#pragma unroll
    for (int e = 0; e < NEXP; e++) p[e] = 0.f;
    const float* g = gw + (size_t)lane * 64;
#pragma unroll
    for (int j = 0; j < 8; j++)
#pragma unroll
        for (int e = 0; e < NEXP; e++) p[e] += xv[j] * g[j * 8 + e];
#pragma unroll
    for (int e = 0; e < NEXP; e++) {
        float v = p[e];
        for (int off = 32; off; off >>= 1) v += __shfl_xor(v, off, 64);
        p[e] = v;
    }
    if (lane == 0) {
        float l[NEXP];
#pragma unroll
        for (int e = 0; e < NEXP; e++) l[e] = p[e] + gb[e];
        float m = l[0];
#pragma unroll
        for (int e = 1; e < NEXP; e++) m = fmaxf(m, l[e]);
        float ex[NEXP], s = 0.f;
#pragma unroll
        for (int e = 0; e < NEXP; e++) { ex[e] = expf(l[e] - m); s += ex[e]; }
        int e0 = 0; float m0 = l[0];
#pragma unroll
        for (int e = 1; e < NEXP; e++) if (l[e] > m0) { m0 = l[e]; e0 = e; }
        int e1 = -1; float m1 = -FLT_MAX;
#pragma unroll
        for (int e = 0; e < NEXP; e++) if (e != e0 && l[e] > m1) { m1 = l[e]; e1 = e; }
        float inv = 1.f / s;
        top_e[2 * n + 0] = e0;
        top_e[2 * n + 1] = e1;
        top_w[2 * n + 0] = ex[0] * inv;   // slot-indexed probs (reference quirk)
        top_w[2 * n + 1] = ex[1] * inv;
        atomicAdd(&scnt[e0], 1);
        atomicAdd(&scnt[e1], 1);
    }
    __syncthreads();
    if (tid < NEXP) atomicAdd(&meta[tid], scnt[tid]);
}

// ---------------- scatter (scan inlined from counts) ----------------
__global__ __launch_bounds__(256)
void scatter_kernel(const int* __restrict__ top_e, const float* __restrict__ top_w,
                    int* __restrict__ meta, int* __restrict__ entry_tok,
                    float* __restrict__ entry_w)
{
    int offs[NEXP];
    {
        int off = 0;
#pragma unroll
        for (int e = 0; e < NEXP; e++) {
            offs[e] = off;
            off += ((meta[e] + 63) >> 6) << 6;
        }
    }
    int n = blockIdx.x * 256 + threadIdx.x;
    int lane = threadIdx.x & 63;
#pragma unroll
    for (int j = 0; j < 2; j++) {
        int e = top_e[2 * n + j];
        float ww = top_w[2 * n + j];
        int pos = 0;
        for (int ex = 0; ex < NEXP; ex++) {
            unsigned long long m = __ballot(e == ex);
            if (e == ex) {
                int leader = __ffsll(m) - 1;
                int base = 0;
                if (lane == leader) base = atomicAdd(&meta[8 + ex], __popcll(m));
                base = __shfl(base, leader, 64);
                pos = offs[ex] + base + __popcll(m & ((1ull << lane) - 1ull));
            }
        }
        entry_tok[pos] = n;
        entry_w[pos] = ww;
    }
}

// ---------------- pack weights: W[mat][k][n] f32 -> MFMA-B-fragment order f16 ----
// Packed: chunk ci = (mat*32 + c16)*16 + kc holds B[16 cols][32 k] as one 1KB
// wave fragment: lane l -> col = c16*16 + (l&15), k = kc*32 + (l>>4)*8 + j.
__global__ __launch_bounds__(256)
void pack_w(const float* __restrict__ W1, const float* __restrict__ W2,
            const float* __restrict__ W3, _Float16* __restrict__ Wt)
{
    int bid = blockIdx.x;
    int mat = bid >> 4;            // 0..23
    int kc  = bid & 15;            // 32-k chunk
    const float* src = (mat < 8) ? W1 + (size_t)mat * MATSZ
                     : (mat < 16) ? W2 + (size_t)(mat - 8) * MATSZ
                                  : W3 + (size_t)(mat - 16) * MATSZ;
    int tid = threadIdx.x;
    int w = tid >> 6, lane = tid & 63;
    int l15 = lane & 15, l4 = lane >> 4;
#pragma unroll
    for (int i = 0; i < 8; i++) {
        int c16 = w * 8 + i;
        int col = c16 * 16 + l15;
        int k0 = kc * 32 + l4 * 8;
        half8 h;
#pragma unroll
        for (int j = 0; j < 8; j++)
            h[j] = (_Float16)src[(size_t)(k0 + j) * DIM + col];
        _Float16* dst = Wt + (size_t)mat * MATSZ + (size_t)(c16 * 16 + kc) * 512 + lane * 8;
        *(half8*)dst = h;
    }
}

// ---------------- fused 3-layer expert MLP ----------------
__global__ __launch_bounds__(256, 1)
void fused_mlp(const _Float16* __restrict__ xh, const _Float16* __restrict__ wt,
               const float* __restrict__ b1, const float* __restrict__ b2,
               const float* __restrict__ b3, float* __restrict__ out,
               const int* __restrict__ meta, const int* __restrict__ entry_tok,
               const float* __restrict__ entry_w)
{
    __shared__ _Float16 hbuf[64 * DIM];   // 64 KB, swizzled cols
    __shared__ int   rtok[64];
    __shared__ float rw[64];

    int bid = blockIdx.x;
    int e = bid & 7;                       // XCD affinity: blockIdx % 8 -> XCD
    int j = bid >> 3;
    int cnt = 0, base = 0;
    {
        int off = 0;
#pragma unroll
        for (int ee = 0; ee < NEXP; ee++) {
            int c = meta[ee];
            if (ee == e) { cnt = c; base = off; }
            off += ((c + 63) >> 6) << 6;
        }
    }
    if (j >= ((cnt + 63) >> 6)) return;
    int row0 = base + (j << 6);

    int tid = threadIdx.x;
    int w = tid >> 6, l = tid & 63;
    int l15 = l & 15, l4 = l >> 4;

    if (tid < 64) {
        rtok[tid] = entry_tok[row0 + tid]; // pad slots: poison (<0)
        rw[tid]   = entry_w[row0 + tid];
    }
    __syncthreads();

    // fill hbuf with gathered x rows: 4 threads/row, 128 cols each
    {
        int row = tid >> 2;
        int c0 = (tid & 3) * 128;
        int tk = rtok[row]; if (tk < 0) tk = 0;   // garbage ok, dropped at epilogue
        const _Float16* src = xh + (size_t)tk * DIM + c0;
        int f = swz(row);
        _Float16* dst = hbuf + row * DIM;
#pragma unroll
        for (int q = 0; q < 16; q++) {
            half8 v = *(const half8*)(src + q * 8);
            *(half8*)(dst + ((c0 + q * 8) ^ f)) = v;
        }
    }
    __syncthreads();

    int colb = w * 128 + l15;              // wave w owns cols [w*128, w*128+128)
    f32x4 acc[4][8];

    // one layer: A from hbuf (64 rows), B from packed global, depth-1 prefetch
    auto run_layer = [&](const _Float16* __restrict__ Wp) {
#pragma unroll
        for (int rg = 0; rg < 4; rg++)
#pragma unroll
            for (int cg = 0; cg < 8; cg++) acc[rg][cg] = (f32x4){0.f, 0.f, 0.f, 0.f};
        // packed base for this wave: chunks (w*8+cg)*16 + kc, each 512 f16
        const _Float16* wb = Wp + (size_t)(w * 8) * 16 * 512 + l * 8;
        half8 bcur[8], bnxt[8];
#pragma unroll
        for (int cg = 0; cg < 8; cg++)
            bcur[cg] = *(const half8*)(wb + (size_t)(cg * 16) * 512);
        for (int kc = 0; kc < 16; kc++) {
            if (kc < 15) {                 // next kc's B in flight during MFMAs
                const _Float16* wn = wb + (size_t)(kc + 1) * 512;
#pragma unroll
                for (int cg = 0; cg < 8; cg++)
                    bnxt[cg] = *(const half8*)(wn + (size_t)(cg * 16) * 512);
            }
            int koff = kc * 32 + l4 * 8;
            half8 af[4];
#pragma unroll
            for (int rg = 0; rg < 4; rg++) {
                int row = rg * 16 + l15;
                af[rg] = *(const half8*)(hbuf + row * DIM + (koff ^ swz(row)));
            }
#pragma unroll
            for (int rg = 0; rg < 4; rg++)
#pragma unroll
                for (int cg = 0; cg < 8; cg++)
                    acc[rg][cg] = __builtin_amdgcn_mfma_f32_16x16x32_f16(af[rg], bcur[cg], acc[rg][cg], 0, 0, 0);
#pragma unroll
            for (int cg = 0; cg < 8; cg++) bcur[cg] = bnxt[cg];
        }
    };

    // relu(acc + bias) -> hbuf; C/D layout: col=l&15(+16cg), row=l4*4+r(+16rg)
    auto writeback = [&](const float* __restrict__ Bias) {
        float bs[8];
#pragma unroll
        for (int cg = 0; cg < 8; cg++) bs[cg] = Bias[e * DIM + colb + cg * 16];
        __syncthreads();                   // all waves' hbuf reads done
#pragma unroll
        for (int rg = 0; rg < 4; rg++)
#pragma unroll
            for (int r = 0; r < 4; r++) {
                int row = rg * 16 + l4 * 4 + r;
                int f = swz(row);
                _Float16* dst = hbuf + row * DIM;
#pragma unroll
                for (int cg = 0; cg < 8; cg++)
                    dst[(colb + cg * 16) ^ f] = (_Float16)fmaxf(acc[rg][cg][r] + bs[cg], 0.f);
            }
        __syncthreads();
    };

    run_layer(wt + (size_t)e * MATSZ);        writeback(b1);
    run_layer(wt + (size_t)(8 + e) * MATSZ);  writeback(b2);
    run_layer(wt + (size_t)(16 + e) * MATSZ);

    // layer-3 epilogue: out[tok] += entry_w * relu(acc + b3)
    float bs[8];
#pragma unroll
    for (int cg = 0; cg < 8; cg++) bs[cg] = b3[e * DIM + colb + cg * 16];
#pragma unroll
    for (int rg = 0; rg < 4; rg++)
#pragma unroll
        for (int r = 0; r < 4; r++) {
            int row = rg * 16 + l4 * 4 + r;
            int tok = rtok[row];
            if (tok >= 0) {
                float ww = rw[row];
                float* op = out + (size_t)tok * DIM + colb;
#pragma unroll
                for (int cg = 0; cg < 8; cg++) {
                    float v = fmaxf(acc[rg][cg][r] + bs[cg], 0.f);
                    atomicAdd(op + cg * 16, ww * v);
                }
            }
        }
}

extern "C" void kernel_launch(void* const* d_in, const int* in_sizes, int n_in,
                              void* d_out, int out_size, void* d_ws, size_t ws_size,
                              hipStream_t stream)
{
    const float* x      = (const float*)d_in[0];
    const float* gate_w = (const float*)d_in[1];
    const float* gate_b = (const float*)d_in[2];
    const float* w1     = (const float*)d_in[3];
    const float* b1     = (const float*)d_in[4];
    const float* w2     = (const float*)d_in[5];
    const float* b2     = (const float*)d_in[6];
    const float* w3     = (const float*)d_in[7];
    const float* b3     = (const float*)d_in[8];
    float* out = (float*)d_out;

    char* ws = (char*)d_ws;
    int*      meta      = (int*)(ws + META_OFF);
    int*      top_e     = (int*)(ws + TOPE_OFF);
    float*    top_w     = (float*)(ws + TOPW_OFF);
    int*      entry_tok = (int*)(ws + ETOK_OFF);
    float*    entry_w   = (float*)(ws + EW_OFF);
    _Float16* xh        = (_Float16*)(ws + XH_OFF);
    _Float16* wt        = (_Float16*)(ws + WT_OFF);

    hipMemsetAsync(meta, 0, 256, stream);

    gate_kernel<<<NTOK / 4, 256, 0, stream>>>(x, gate_w, gate_b, top_e, top_w, xh, meta, out);
    scatter_kernel<<<NTOK / 256, 256, 0, stream>>>(top_e, top_w, meta, entry_tok, entry_w);
    pack_w<<<24 * 16, 256, 0, stream>>>(w1, w2, w3, wt);

    fused_mlp<<<NEXP * MAXTE, 256, 0, stream>>>(xh, wt, b1, b2, b3, out,
                                                meta, entry_tok, entry_w);
}